// Round 2
// baseline (2461.107 us; speedup 1.0000x reference)
//
#include <hip/hip_runtime.h>
#include <hip/hip_bf16.h>

#define NN 50000
#define NE 800000
#define NG 500
#define NF 128
#define NH 64

typedef unsigned int u32;
typedef unsigned short u16;

__device__ __forceinline__ float bflo(u32 p){ return __uint_as_float(p << 16); }
__device__ __forceinline__ float bfhi(u32 p){ return __uint_as_float(p & 0xffff0000u); }
__device__ __forceinline__ float bf1(u16 v){ return __uint_as_float(((u32)v) << 16); }

__device__ __forceinline__ void cv8(uint4 q, float* dst){
  dst[0]=bflo(q.x); dst[1]=bfhi(q.x);
  dst[2]=bflo(q.y); dst[3]=bfhi(q.y);
  dst[4]=bflo(q.z); dst[5]=bfhi(q.z);
  dst[6]=bflo(q.w); dst[7]=bfhi(q.w);
}

// ---- dtype probe: low u16 of each word has bf16-plausible exponent iff input is bf16
__global__ void k_detect(const u32* __restrict__ x, int* __restrict__ flag){
  int lane = threadIdx.x;           // 64 threads
  u32 w = x[lane];
  u32 lo = w & 0xFFFFu;
  u32 e = (lo >> 7) & 0xFFu;
  bool vote = (e >= 0x60u && e <= 0x8Fu);
  unsigned long long m = __ballot(vote);
  if (lane == 0) flag[0] = (__popcll(m) >= 32) ? 1 : 0;
}

// ---- graph boundaries from sorted batch
__global__ void k_bounds(const int* __restrict__ batch, int* __restrict__ starts){
  int g = threadIdx.x;
  if (g > NG) return;
  int lo = 0, hi = NN;
  while (lo < hi){ int mid = (lo + hi) >> 1; if (batch[mid] < g) lo = mid + 1; else hi = mid; }
  starts[g] = lo;
}

// ---- transform: t = x @ Wt + bt ; accumulate column sum/sumsq for BN
__global__ __launch_bounds__(256) void k_transform(const void* __restrict__ x,
    const void* __restrict__ Wt, const void* __restrict__ bt, const int* __restrict__ flag,
    float* __restrict__ t, float* __restrict__ s1, float* __restrict__ s2){
  __shared__ float sW[NF*NH];     // 32 KB
  __shared__ float sRed[8*NH];
  int tid = threadIdx.x;
  int bf = flag[0];
  if (bf){
    for (int i = tid*8; i < NF*NH; i += 2048){
      uint4 q = *(const uint4*)((const u16*)Wt + i);
      cv8(q, &sW[i]);
    }
  } else {
    for (int i = tid*4; i < NF*NH; i += 1024){
      *(float4*)&sW[i] = *(const float4*)((const float*)Wt + i);
    }
  }
  __syncthreads();
  int tx = tid & 63, ty = tid >> 6;
  int row0 = blockIdx.x*64 + ty*16;
  float b = bf ? bf1(((const u16*)bt)[tx]) : ((const float*)bt)[tx];
  float ls1 = 0.f, ls2 = 0.f;
  for (int i = 0; i < 16; i++){
    int row = row0 + i;
    if (row >= NN) break;
    float acc = b;
    if (bf){
      const uint4* xr = (const uint4*)((const u16*)x + (size_t)row*NF);
      #pragma unroll
      for (int k8 = 0; k8 < 16; k8++){
        float f[8]; cv8(xr[k8], f);
        int kb = k8*8;
        #pragma unroll
        for (int j = 0; j < 8; j++) acc += f[j] * sW[(kb+j)*NH + tx];
      }
    } else {
      const float4* xr = (const float4*)((const float*)x + (size_t)row*NF);
      #pragma unroll
      for (int k4 = 0; k4 < 32; k4++){
        float4 f = xr[k4];
        int kb = k4*4;
        acc += f.x*sW[(kb+0)*NH+tx];
        acc += f.y*sW[(kb+1)*NH+tx];
        acc += f.z*sW[(kb+2)*NH+tx];
        acc += f.w*sW[(kb+3)*NH+tx];
      }
    }
    t[(size_t)row*NH + tx] = acc;
    ls1 += acc; ls2 += acc*acc;
  }
  sRed[ty*NH + tx] = ls1;
  sRed[(4+ty)*NH + tx] = ls2;
  __syncthreads();
  if (ty == 0){
    float a1 = sRed[tx] + sRed[NH+tx] + sRed[2*NH+tx] + sRed[3*NH+tx];
    float a2 = sRed[4*NH+tx] + sRed[5*NH+tx] + sRed[6*NH+tx] + sRed[7*NH+tx];
    unsafeAtomicAdd(&s1[tx], a1);
    unsafeAtomicAdd(&s2[tx], a2);
  }
}

// ---- fold BN: scale = gamma*rsqrt(var+eps), shift = beta - mean*scale
__global__ void k_bnfinal(const float* __restrict__ s1, const float* __restrict__ s2,
    const void* __restrict__ gamma, const void* __restrict__ beta, int ofs,
    const int* __restrict__ flag, float* __restrict__ scA, float* __restrict__ shB){
  int c = threadIdx.x;
  int bf = flag[0];
  float g  = bf ? bf1(((const u16*)gamma)[ofs+c]) : ((const float*)gamma)[ofs+c];
  float be = bf ? bf1(((const u16*)beta)[ofs+c])  : ((const float*)beta)[ofs+c];
  float mean = s1[c] * (1.f/NN);
  float var  = s2[c] * (1.f/NN) - mean*mean;
  float r = rsqrtf(fmaxf(var, 0.f) + 1e-5f);
  float sc = g * r;
  scA[c] = sc;
  shB[c] = be - mean*sc;
}

// ---- per-graph: z = t*scale+shift, write h, emit mean & std per column
__global__ __launch_bounds__(256) void k_embed(const float* __restrict__ t,
    const float* __restrict__ scA, const float* __restrict__ shB,
    float* __restrict__ h, const int* __restrict__ starts, const int* __restrict__ flag,
    void* __restrict__ dout, int layer){
  __shared__ float sRed[8*NH];
  int g = blockIdx.x;
  int tx = threadIdx.x & 63, ty = threadIdx.x >> 6;
  int st = starts[g], en = starts[g+1];
  float sc = scA[tx], sh = shB[tx];
  float ls1 = 0.f, ls2 = 0.f;
  for (int n = st + ty; n < en; n += 4){
    float z = t[(size_t)n*NH + tx] * sc + sh;
    h[(size_t)n*NH + tx] = z;
    ls1 += z; ls2 += z*z;
  }
  sRed[ty*NH + tx] = ls1;
  sRed[(4+ty)*NH + tx] = ls2;
  __syncthreads();
  if (ty == 0){
    float a1 = sRed[tx] + sRed[NH+tx] + sRed[2*NH+tx] + sRed[3*NH+tx];
    float a2 = sRed[4*NH+tx] + sRed[5*NH+tx] + sRed[6*NH+tx] + sRed[7*NH+tx];
    int cnt = en - st;
    float inv = 1.f / (float)max(cnt, 1);
    float m = a1 * inv;
    float var = a2 * inv - m*m;
    float s = sqrtf(fmaxf(var, 0.f));
    size_t eidx = ((size_t)layer*NG + g)*NH + tx;
    size_t sidx = (size_t)4*NG*NH + eidx;
    if (flag[0]){
      ((__hip_bfloat16*)dout)[eidx] = __float2bfloat16(m);
      ((__hip_bfloat16*)dout)[sidx] = __float2bfloat16(s);
    } else {
      ((float*)dout)[eidx] = m;
      ((float*)dout)[sidx] = s;
    }
  }
}

// ---- edge scatter: agg[dst] += h[src]; one thread per (edge, float4-chunk)
__global__ __launch_bounds__(256) void k_scatter(const int* __restrict__ ei,
    const float* __restrict__ h, float* __restrict__ agg){
  int gid = blockIdx.x*256 + threadIdx.x;
  int e = gid >> 4, q = gid & 15;
  int src = ei[e], dst = ei[NE + e];
  float4 v = *(const float4*)&h[(size_t)src*NH + q*4];
  float* a = &agg[(size_t)dst*NH + q*4];
  unsafeAtomicAdd(a+0, v.x);
  unsafeAtomicAdd(a+1, v.y);
  unsafeAtomicAdd(a+2, v.z);
  unsafeAtomicAdd(a+3, v.w);
}

// ---- GIN MLP: t = relu(relu((h+agg)@W1)@W2), accumulate BN stats
__global__ __launch_bounds__(256) void k_mlp(const float* __restrict__ h, const float* __restrict__ agg,
    const void* __restrict__ W1, const void* __restrict__ W2, int wofs, const int* __restrict__ flag,
    float* __restrict__ t, float* __restrict__ s1, float* __restrict__ s2){
  __shared__ float sU[64*NH];    // 16 KB
  __shared__ float sV[64*NH];    // 16 KB
  __shared__ float sW1[NH*NH];   // 16 KB (reused for stat reduction at the end)
  __shared__ float sW2[NH*NH];   // 16 KB
  int tid = threadIdx.x;
  int bf = flag[0];
  if (bf){
    const u16* w1 = (const u16*)W1 + wofs;
    const u16* w2 = (const u16*)W2 + wofs;
    for (int i = tid*8; i < NH*NH; i += 2048){
      cv8(*(const uint4*)(w1 + i), &sW1[i]);
      cv8(*(const uint4*)(w2 + i), &sW2[i]);
    }
  } else {
    const float* w1 = (const float*)W1 + wofs;
    const float* w2 = (const float*)W2 + wofs;
    for (int i = tid*4; i < NH*NH; i += 1024){
      *(float4*)&sW1[i] = *(const float4*)(w1 + i);
      *(float4*)&sW2[i] = *(const float4*)(w2 + i);
    }
  }
  int base = blockIdx.x*64*NH;
  int nrows = min(64, NN - blockIdx.x*64);
  for (int i = tid*4; i < nrows*NH; i += 1024){
    float4 a = *(const float4*)&h[base + i];
    float4 b = *(const float4*)&agg[base + i];
    a.x += b.x; a.y += b.y; a.z += b.z; a.w += b.w;
    *(float4*)&sU[i] = a;
  }
  __syncthreads();
  int tx = tid & 63, ty = tid >> 6;
  // phase A: V = relu(U @ W1)
  for (int i = 0; i < 16; i++){
    int row = ty*16 + i;
    if (row >= nrows) break;
    const float4* ur = (const float4*)&sU[row*NH];
    float acc = 0.f;
    #pragma unroll
    for (int k4 = 0; k4 < 16; k4++){
      float4 u = ur[k4];
      acc += u.x*sW1[(k4*4+0)*NH+tx];
      acc += u.y*sW1[(k4*4+1)*NH+tx];
      acc += u.z*sW1[(k4*4+2)*NH+tx];
      acc += u.w*sW1[(k4*4+3)*NH+tx];
    }
    sV[row*NH + tx] = fmaxf(acc, 0.f);
  }
  __syncthreads();
  // phase B: T = relu(V @ W2)
  float ls1 = 0.f, ls2 = 0.f;
  for (int i = 0; i < 16; i++){
    int row = ty*16 + i;
    if (row >= nrows) break;
    const float4* vr = (const float4*)&sV[row*NH];
    float acc = 0.f;
    #pragma unroll
    for (int k4 = 0; k4 < 16; k4++){
      float4 v = vr[k4];
      acc += v.x*sW2[(k4*4+0)*NH+tx];
      acc += v.y*sW2[(k4*4+1)*NH+tx];
      acc += v.z*sW2[(k4*4+2)*NH+tx];
      acc += v.w*sW2[(k4*4+3)*NH+tx];
    }
    float tv = fmaxf(acc, 0.f);
    t[base + row*NH + tx] = tv;
    ls1 += tv; ls2 += tv*tv;
  }
  __syncthreads();
  sW1[ty*NH + tx] = ls1;
  sW1[(4+ty)*NH + tx] = ls2;
  __syncthreads();
  if (ty == 0){
    float a1 = sW1[tx] + sW1[NH+tx] + sW1[2*NH+tx] + sW1[3*NH+tx];
    float a2 = sW1[4*NH+tx] + sW1[5*NH+tx] + sW1[6*NH+tx] + sW1[7*NH+tx];
    unsafeAtomicAdd(&s1[tx], a1);
    unsafeAtomicAdd(&s2[tx], a2);
  }
}

extern "C" void kernel_launch(void* const* d_in, const int* in_sizes, int n_in,
                              void* d_out, int out_size, void* d_ws, size_t ws_size,
                              hipStream_t stream) {
  const void* x    = d_in[0];
  const int* ei    = (const int*)d_in[1];
  const int* batch = (const int*)d_in[2];
  const void* Wt   = d_in[3];
  const void* bt   = d_in[4];
  const void* g0   = d_in[5];
  const void* b0   = d_in[6];
  const void* W1   = d_in[7];
  const void* W2   = d_in[8];
  const void* gs   = d_in[9];
  const void* bs   = d_in[10];

  float* hbuf = (float*)d_ws;           // 3.2M f32
  float* tbuf = hbuf + (size_t)NN*NH;   // 3.2M f32
  float* agg  = tbuf + (size_t)NN*NH;   // 3.2M f32
  float* s1   = agg  + (size_t)NN*NH;   // 64
  float* s2   = s1 + NH;                // 64
  float* scA  = s2 + NH;                // 64
  float* shB  = scA + NH;               // 64
  int* starts = (int*)(shB + NH);       // 501
  int* flag   = starts + 512;           // 1

  hipMemsetAsync(s1, 0, 2*NH*sizeof(float), stream);
  k_detect<<<1, 64, 0, stream>>>((const u32*)x, flag);
  k_bounds<<<1, 512, 0, stream>>>(batch, starts);
  k_transform<<<(NN+63)/64, 256, 0, stream>>>(x, Wt, bt, flag, tbuf, s1, s2);
  k_bnfinal<<<1, NH, 0, stream>>>(s1, s2, g0, b0, 0, flag, scA, shB);
  k_embed<<<NG, 256, 0, stream>>>(tbuf, scA, shB, hbuf, starts, flag, d_out, 0);

  for (int l = 0; l < 3; l++){
    hipMemsetAsync(agg, 0, (size_t)NN*NH*sizeof(float), stream);
    hipMemsetAsync(s1, 0, 2*NH*sizeof(float), stream);
    k_scatter<<<(NE*16)/256, 256, 0, stream>>>(ei, hbuf, agg);
    k_mlp<<<(NN+63)/64, 256, 0, stream>>>(hbuf, agg, W1, W2, l*NH*NH, flag, tbuf, s1, s2);
    k_bnfinal<<<1, NH, 0, stream>>>(s1, s2, gs, bs, l*NH, flag, scA, shB);
    k_embed<<<NG, 256, 0, stream>>>(tbuf, scA, shB, hbuf, starts, flag, d_out, l+1);
  }
}

// Round 3
// 856.790 us; speedup vs baseline: 2.8725x; 2.8725x over previous
//
#include <hip/hip_runtime.h>
#include <hip/hip_bf16.h>

#define NN 50000
#define NE 800000
#define NG 500
#define NF 128
#define NH 64

typedef unsigned int u32;
typedef unsigned short u16;

__device__ __forceinline__ float bflo(u32 p){ return __uint_as_float(p << 16); }
__device__ __forceinline__ float bfhi(u32 p){ return __uint_as_float(p & 0xffff0000u); }
__device__ __forceinline__ float bf1(u16 v){ return __uint_as_float(((u32)v) << 16); }

__device__ __forceinline__ void cv8(uint4 q, float* dst){
  dst[0]=bflo(q.x); dst[1]=bfhi(q.x);
  dst[2]=bflo(q.y); dst[3]=bfhi(q.y);
  dst[4]=bflo(q.z); dst[5]=bfhi(q.z);
  dst[6]=bflo(q.w); dst[7]=bfhi(q.w);
}

// ---- dtype probe: low u16 of each word has bf16-plausible exponent iff input is bf16
__global__ void k_detect(const u32* __restrict__ x, int* __restrict__ flag){
  int lane = threadIdx.x;           // 64 threads
  u32 w = x[lane];
  u32 lo = w & 0xFFFFu;
  u32 e = (lo >> 7) & 0xFFu;
  bool vote = (e >= 0x60u && e <= 0x8Fu);
  unsigned long long m = __ballot(vote);
  if (lane == 0) flag[0] = (__popcll(m) >= 32) ? 1 : 0;
}

// ---- graph boundaries from sorted batch
__global__ void k_bounds(const int* __restrict__ batch, int* __restrict__ starts){
  int g = threadIdx.x;
  if (g > NG) return;
  int lo = 0, hi = NN;
  while (lo < hi){ int mid = (lo + hi) >> 1; if (batch[mid] < g) lo = mid + 1; else hi = mid; }
  starts[g] = lo;
}

// ---- CSR build step 1: in-degree count
__global__ __launch_bounds__(256) void k_count(const int* __restrict__ ei, int* __restrict__ deg){
  int e = blockIdx.x*256 + threadIdx.x;
  if (e >= NE) return;
  atomicAdd(&deg[ei[NE + e]], 1);
}

// ---- CSR build step 2: exclusive scan of deg -> rowptr (+ cursor copy), single block
__global__ __launch_bounds__(1024) void k_scan(const int* __restrict__ deg,
    int* __restrict__ rowptr, int* __restrict__ cursor){
  __shared__ int part[1024];
  int t = threadIdx.x;
  const int CH = (NN + 1023)/1024;  // 49
  int lo = t*CH, hi = min(lo+CH, NN);
  int s = 0;
  for (int i = lo; i < hi; i++) s += deg[i];
  part[t] = s;
  __syncthreads();
  for (int off = 1; off < 1024; off <<= 1){
    int v = (t >= off) ? part[t-off] : 0;
    __syncthreads();
    part[t] += v;
    __syncthreads();
  }
  int run = (t == 0) ? 0 : part[t-1];
  for (int i = lo; i < hi; i++){
    rowptr[i] = run; cursor[i] = run;
    run += deg[i];
  }
  if (t == 0) rowptr[NN] = NE;
}

// ---- CSR build step 3: fill src lists (order within a node irrelevant: sum is commutative)
__global__ __launch_bounds__(256) void k_fill(const int* __restrict__ ei,
    int* __restrict__ cursor, int* __restrict__ csr){
  int e = blockIdx.x*256 + threadIdx.x;
  if (e >= NE) return;
  int dst = ei[NE + e];
  int slot = atomicAdd(&cursor[dst], 1);
  csr[slot] = ei[e];
}

// ---- transform: t = x @ Wt + bt ; accumulate column sum/sumsq for BN
__global__ __launch_bounds__(256) void k_transform(const void* __restrict__ x,
    const void* __restrict__ Wt, const void* __restrict__ bt, const int* __restrict__ flag,
    float* __restrict__ t, float* __restrict__ s1, float* __restrict__ s2){
  __shared__ float sW[NF*NH];     // 32 KB
  __shared__ float sRed[8*NH];
  int tid = threadIdx.x;
  int bf = flag[0];
  if (bf){
    for (int i = tid*8; i < NF*NH; i += 2048){
      uint4 q = *(const uint4*)((const u16*)Wt + i);
      cv8(q, &sW[i]);
    }
  } else {
    for (int i = tid*4; i < NF*NH; i += 1024){
      *(float4*)&sW[i] = *(const float4*)((const float*)Wt + i);
    }
  }
  __syncthreads();
  int tx = tid & 63, ty = tid >> 6;
  int row0 = blockIdx.x*64 + ty*16;
  float b = bf ? bf1(((const u16*)bt)[tx]) : ((const float*)bt)[tx];
  float ls1 = 0.f, ls2 = 0.f;
  for (int i = 0; i < 16; i++){
    int row = row0 + i;
    if (row >= NN) break;
    float acc = b;
    if (bf){
      const uint4* xr = (const uint4*)((const u16*)x + (size_t)row*NF);
      #pragma unroll
      for (int k8 = 0; k8 < 16; k8++){
        float f[8]; cv8(xr[k8], f);
        int kb = k8*8;
        #pragma unroll
        for (int j = 0; j < 8; j++) acc += f[j] * sW[(kb+j)*NH + tx];
      }
    } else {
      const float4* xr = (const float4*)((const float*)x + (size_t)row*NF);
      #pragma unroll
      for (int k4 = 0; k4 < 32; k4++){
        float4 f = xr[k4];
        int kb = k4*4;
        acc += f.x*sW[(kb+0)*NH+tx];
        acc += f.y*sW[(kb+1)*NH+tx];
        acc += f.z*sW[(kb+2)*NH+tx];
        acc += f.w*sW[(kb+3)*NH+tx];
      }
    }
    t[(size_t)row*NH + tx] = acc;
    ls1 += acc; ls2 += acc*acc;
  }
  sRed[ty*NH + tx] = ls1;
  sRed[(4+ty)*NH + tx] = ls2;
  __syncthreads();
  if (ty == 0){
    float a1 = sRed[tx] + sRed[NH+tx] + sRed[2*NH+tx] + sRed[3*NH+tx];
    float a2 = sRed[4*NH+tx] + sRed[5*NH+tx] + sRed[6*NH+tx] + sRed[7*NH+tx];
    unsafeAtomicAdd(&s1[tx], a1);
    unsafeAtomicAdd(&s2[tx], a2);
  }
}

// ---- fold BN: scale = gamma*rsqrt(var+eps), shift = beta - mean*scale
__global__ void k_bnfinal(const float* __restrict__ s1, const float* __restrict__ s2,
    const void* __restrict__ gamma, const void* __restrict__ beta, int ofs,
    const int* __restrict__ flag, float* __restrict__ scA, float* __restrict__ shB){
  int c = threadIdx.x;
  int bf = flag[0];
  float g  = bf ? bf1(((const u16*)gamma)[ofs+c]) : ((const float*)gamma)[ofs+c];
  float be = bf ? bf1(((const u16*)beta)[ofs+c])  : ((const float*)beta)[ofs+c];
  float mean = s1[c] * (1.f/NN);
  float var  = s2[c] * (1.f/NN) - mean*mean;
  float r = rsqrtf(fmaxf(var, 0.f) + 1e-5f);
  float sc = g * r;
  scA[c] = sc;
  shB[c] = be - mean*sc;
}

// ---- per-graph: z = t*scale+shift, write h, emit mean & std per column
__global__ __launch_bounds__(256) void k_embed(const float* __restrict__ t,
    const float* __restrict__ scA, const float* __restrict__ shB,
    float* __restrict__ h, const int* __restrict__ starts, const int* __restrict__ flag,
    void* __restrict__ dout, int layer){
  __shared__ float sRed[8*NH];
  int g = blockIdx.x;
  int tx = threadIdx.x & 63, ty = threadIdx.x >> 6;
  int st = starts[g], en = starts[g+1];
  float sc = scA[tx], sh = shB[tx];
  float ls1 = 0.f, ls2 = 0.f;
  for (int n = st + ty; n < en; n += 4){
    float z = t[(size_t)n*NH + tx] * sc + sh;
    h[(size_t)n*NH + tx] = z;
    ls1 += z; ls2 += z*z;
  }
  sRed[ty*NH + tx] = ls1;
  sRed[(4+ty)*NH + tx] = ls2;
  __syncthreads();
  if (ty == 0){
    float a1 = sRed[tx] + sRed[NH+tx] + sRed[2*NH+tx] + sRed[3*NH+tx];
    float a2 = sRed[4*NH+tx] + sRed[5*NH+tx] + sRed[6*NH+tx] + sRed[7*NH+tx];
    int cnt = en - st;
    float inv = 1.f / (float)max(cnt, 1);
    float m = a1 * inv;
    float var = a2 * inv - m*m;
    float s = sqrtf(fmaxf(var, 0.f));
    size_t eidx = ((size_t)layer*NG + g)*NH + tx;
    size_t sidx = (size_t)4*NG*NH + eidx;
    if (flag[0]){
      ((__hip_bfloat16*)dout)[eidx] = __float2bfloat16(m);
      ((__hip_bfloat16*)dout)[sidx] = __float2bfloat16(s);
    } else {
      ((float*)dout)[eidx] = m;
      ((float*)dout)[sidx] = s;
    }
  }
}

// ---- GIN MLP with FUSED gather: U = h[node] + sum_{src in CSR[node]} h[src];
//      t = relu(relu(U@W1)@W2); accumulate BN stats
__global__ __launch_bounds__(256) void k_mlp(const float* __restrict__ h,
    const int* __restrict__ rowptr, const int* __restrict__ csr,
    const void* __restrict__ W1, const void* __restrict__ W2, int wofs,
    const int* __restrict__ flag,
    float* __restrict__ t, float* __restrict__ s1, float* __restrict__ s2){
  __shared__ float sU[64*NH];    // 16 KB
  __shared__ float sV[64*NH];    // 16 KB
  __shared__ float sW1[NH*NH];   // 16 KB (reused for stat reduction at the end)
  __shared__ float sW2[NH*NH];   // 16 KB
  int tid = threadIdx.x;
  int bf = flag[0];
  if (bf){
    const u16* w1 = (const u16*)W1 + wofs;
    const u16* w2 = (const u16*)W2 + wofs;
    for (int i = tid*8; i < NH*NH; i += 2048){
      cv8(*(const uint4*)(w1 + i), &sW1[i]);
      cv8(*(const uint4*)(w2 + i), &sW2[i]);
    }
  } else {
    const float* w1 = (const float*)W1 + wofs;
    const float* w2 = (const float*)W2 + wofs;
    for (int i = tid*4; i < NH*NH; i += 1024){
      *(float4*)&sW1[i] = *(const float4*)(w1 + i);
      *(float4*)&sW2[i] = *(const float4*)(w2 + i);
    }
  }
  int node0 = blockIdx.x*64;
  int nrows = min(64, NN - node0);
  int wid = tid >> 6, lane = tid & 63;
  int chunk = lane & 15, epar = lane >> 4;
  // gather phase: each wave owns rows wid, wid+4, ... ; lane = 4 edge-slots x 16 float4-chunks
  for (int r = wid; r < nrows; r += 4){
    int node = node0 + r;
    int beg = rowptr[node], en = rowptr[node+1];
    float4 acc;
    if (epar == 0) acc = *(const float4*)&h[(size_t)node*NH + chunk*4];  // self term (1+eps)*h, eps=0
    else { acc.x = 0.f; acc.y = 0.f; acc.z = 0.f; acc.w = 0.f; }
    for (int j = beg + epar; j < en; j += 4){
      int src = csr[j];
      float4 v = *(const float4*)&h[(size_t)src*NH + chunk*4];
      acc.x += v.x; acc.y += v.y; acc.z += v.z; acc.w += v.w;
    }
    acc.x += __shfl_xor(acc.x, 16); acc.y += __shfl_xor(acc.y, 16);
    acc.z += __shfl_xor(acc.z, 16); acc.w += __shfl_xor(acc.w, 16);
    acc.x += __shfl_xor(acc.x, 32); acc.y += __shfl_xor(acc.y, 32);
    acc.z += __shfl_xor(acc.z, 32); acc.w += __shfl_xor(acc.w, 32);
    if (epar == 0) *(float4*)&sU[r*NH + chunk*4] = acc;
  }
  __syncthreads();
  int tx = lane, ty = wid;
  // phase A: V = relu(U @ W1)
  for (int i = 0; i < 16; i++){
    int row = ty*16 + i;
    if (row >= nrows) break;
    const float4* ur = (const float4*)&sU[row*NH];
    float acc = 0.f;
    #pragma unroll
    for (int k4 = 0; k4 < 16; k4++){
      float4 u = ur[k4];
      acc += u.x*sW1[(k4*4+0)*NH+tx];
      acc += u.y*sW1[(k4*4+1)*NH+tx];
      acc += u.z*sW1[(k4*4+2)*NH+tx];
      acc += u.w*sW1[(k4*4+3)*NH+tx];
    }
    sV[row*NH + tx] = fmaxf(acc, 0.f);
  }
  __syncthreads();
  // phase B: T = relu(V @ W2)
  float ls1 = 0.f, ls2 = 0.f;
  for (int i = 0; i < 16; i++){
    int row = ty*16 + i;
    if (row >= nrows) break;
    const float4* vr = (const float4*)&sV[row*NH];
    float acc = 0.f;
    #pragma unroll
    for (int k4 = 0; k4 < 16; k4++){
      float4 v = vr[k4];
      acc += v.x*sW2[(k4*4+0)*NH+tx];
      acc += v.y*sW2[(k4*4+1)*NH+tx];
      acc += v.z*sW2[(k4*4+2)*NH+tx];
      acc += v.w*sW2[(k4*4+3)*NH+tx];
    }
    float tv = fmaxf(acc, 0.f);
    t[(size_t)node0*NH + row*NH + tx] = tv;
    ls1 += tv; ls2 += tv*tv;
  }
  __syncthreads();
  sW1[ty*NH + tx] = ls1;
  sW1[(4+ty)*NH + tx] = ls2;
  __syncthreads();
  if (ty == 0){
    float a1 = sW1[tx] + sW1[NH+tx] + sW1[2*NH+tx] + sW1[3*NH+tx];
    float a2 = sW1[4*NH+tx] + sW1[5*NH+tx] + sW1[6*NH+tx] + sW1[7*NH+tx];
    unsafeAtomicAdd(&s1[tx], a1);
    unsafeAtomicAdd(&s2[tx], a2);
  }
}

extern "C" void kernel_launch(void* const* d_in, const int* in_sizes, int n_in,
                              void* d_out, int out_size, void* d_ws, size_t ws_size,
                              hipStream_t stream) {
  const void* x    = d_in[0];
  const int* ei    = (const int*)d_in[1];
  const int* batch = (const int*)d_in[2];
  const void* Wt   = d_in[3];
  const void* bt   = d_in[4];
  const void* g0   = d_in[5];
  const void* b0   = d_in[6];
  const void* W1   = d_in[7];
  const void* W2   = d_in[8];
  const void* gs   = d_in[9];
  const void* bs   = d_in[10];

  float* hbuf = (float*)d_ws;           // NN*NH f32
  float* tbuf = hbuf + (size_t)NN*NH;   // NN*NH f32
  float* s1   = tbuf + (size_t)NN*NH;   // 64
  float* s2   = s1 + NH;                // 64
  float* scA  = s2 + NH;                // 64
  float* shB  = scA + NH;               // 64
  int* starts = (int*)(shB + NH);       // 512
  int* flag   = starts + 512;           // 64 (padded)
  int* deg    = flag + 64;              // NN
  int* rowptr = deg + NN;               // NN+64
  int* cursor = rowptr + NN + 64;       // NN
  int* csr    = cursor + NN;            // NE

  hipMemsetAsync(s1, 0, 2*NH*sizeof(float), stream);
  hipMemsetAsync(deg, 0, NN*sizeof(int), stream);
  k_detect<<<1, 64, 0, stream>>>((const u32*)x, flag);
  k_bounds<<<1, 512, 0, stream>>>(batch, starts);
  // CSR build (reused for all 3 layers)
  k_count<<<(NE+255)/256, 256, 0, stream>>>(ei, deg);
  k_scan<<<1, 1024, 0, stream>>>(deg, rowptr, cursor);
  k_fill<<<(NE+255)/256, 256, 0, stream>>>(ei, cursor, csr);

  k_transform<<<(NN+63)/64, 256, 0, stream>>>(x, Wt, bt, flag, tbuf, s1, s2);
  k_bnfinal<<<1, NH, 0, stream>>>(s1, s2, g0, b0, 0, flag, scA, shB);
  k_embed<<<NG, 256, 0, stream>>>(tbuf, scA, shB, hbuf, starts, flag, d_out, 0);

  for (int l = 0; l < 3; l++){
    hipMemsetAsync(s1, 0, 2*NH*sizeof(float), stream);
    k_mlp<<<(NN+63)/64, 256, 0, stream>>>(hbuf, rowptr, csr, W1, W2, l*NH*NH, flag, tbuf, s1, s2);
    k_bnfinal<<<1, NH, 0, stream>>>(s1, s2, gs, bs, l*NH, flag, scA, shB);
    k_embed<<<NG, 256, 0, stream>>>(tbuf, scA, shB, hbuf, starts, flag, d_out, l+1);
  }
}

// Round 4
// 688.739 us; speedup vs baseline: 3.5734x; 1.2440x over previous
//
#include <hip/hip_runtime.h>
#include <hip/hip_bf16.h>

#define NN 50000
#define NE 800000
#define NG 500
#define NF 128
#define NH 64

typedef unsigned int u32;
typedef unsigned short u16;

__device__ __forceinline__ float bflo(u32 p){ return __uint_as_float(p << 16); }
__device__ __forceinline__ float bfhi(u32 p){ return __uint_as_float(p & 0xffff0000u); }
__device__ __forceinline__ float bf1(u16 v){ return __uint_as_float(((u32)v) << 16); }

__device__ __forceinline__ void cv8(uint4 q, float* dst){
  dst[0]=bflo(q.x); dst[1]=bfhi(q.x);
  dst[2]=bflo(q.y); dst[3]=bfhi(q.y);
  dst[4]=bflo(q.z); dst[5]=bfhi(q.z);
  dst[6]=bflo(q.w); dst[7]=bfhi(q.w);
}

// ---- dtype probe
__global__ void k_detect(const u32* __restrict__ x, int* __restrict__ flag){
  int lane = threadIdx.x;
  u32 w = x[lane];
  u32 lo = w & 0xFFFFu;
  u32 e = (lo >> 7) & 0xFFu;
  bool vote = (e >= 0x60u && e <= 0x8Fu);
  unsigned long long m = __ballot(vote);
  if (lane == 0) flag[0] = (__popcll(m) >= 32) ? 1 : 0;
}

// ---- graph boundaries
__global__ void k_bounds(const int* __restrict__ batch, int* __restrict__ starts){
  int g = threadIdx.x;
  if (g > NG) return;
  int lo = 0, hi = NN;
  while (lo < hi){ int mid = (lo + hi) >> 1; if (batch[mid] < g) lo = mid + 1; else hi = mid; }
  starts[g] = lo;
}

// ---- CSR build
__global__ __launch_bounds__(256) void k_count(const int* __restrict__ ei, int* __restrict__ deg){
  int e = blockIdx.x*256 + threadIdx.x;
  if (e >= NE) return;
  atomicAdd(&deg[ei[NE + e]], 1);
}

__global__ __launch_bounds__(1024) void k_scan(const int* __restrict__ deg,
    int* __restrict__ rowptr, int* __restrict__ cursor){
  __shared__ int part[1024];
  int t = threadIdx.x;
  const int CH = (NN + 1023)/1024;
  int lo = t*CH, hi = min(lo+CH, NN);
  int s = 0;
  for (int i = lo; i < hi; i++) s += deg[i];
  part[t] = s;
  __syncthreads();
  for (int off = 1; off < 1024; off <<= 1){
    int v = (t >= off) ? part[t-off] : 0;
    __syncthreads();
    part[t] += v;
    __syncthreads();
  }
  int run = (t == 0) ? 0 : part[t-1];
  for (int i = lo; i < hi; i++){
    rowptr[i] = run; cursor[i] = run;
    run += deg[i];
  }
  if (t == 0) rowptr[NN] = NE;
}

__global__ __launch_bounds__(256) void k_fill(const int* __restrict__ ei,
    int* __restrict__ cursor, int* __restrict__ csr){
  int e = blockIdx.x*256 + threadIdx.x;
  if (e >= NE) return;
  int dst = ei[NE + e];
  int slot = atomicAdd(&cursor[dst], 1);
  csr[slot] = ei[e];
}

// ---- gather: U[node] = h[node] + sum_{src} h[src]  (one wave per node, no LDS)
__global__ __launch_bounds__(256) void k_gather(const float* __restrict__ h,
    const int* __restrict__ rowptr, const int* __restrict__ csr, float* __restrict__ U){
  int wid = threadIdx.x >> 6, lane = threadIdx.x & 63;
  int node = blockIdx.x*4 + wid;
  if (node >= NN) return;
  int chunk = lane & 15, epar = lane >> 4;
  int beg = rowptr[node], en = rowptr[node+1];
  float4 acc;
  if (epar == 0) acc = *(const float4*)&h[(size_t)node*NH + chunk*4];
  else { acc.x=0.f; acc.y=0.f; acc.z=0.f; acc.w=0.f; }
  for (int j = beg + epar; j < en; j += 4){
    int src = csr[j];
    float4 v = *(const float4*)&h[(size_t)src*NH + chunk*4];
    acc.x += v.x; acc.y += v.y; acc.z += v.z; acc.w += v.w;
  }
  acc.x += __shfl_xor(acc.x, 16); acc.y += __shfl_xor(acc.y, 16);
  acc.z += __shfl_xor(acc.z, 16); acc.w += __shfl_xor(acc.w, 16);
  acc.x += __shfl_xor(acc.x, 32); acc.y += __shfl_xor(acc.y, 32);
  acc.z += __shfl_xor(acc.z, 32); acc.w += __shfl_xor(acc.w, 32);
  if (epar == 0) *(float4*)&U[(size_t)node*NH + chunk*4] = acc;
}

// ---- transform (bf16 fast path): t = x@Wt + bt; stats. lane=row, wave=16 cols.
__global__ __launch_bounds__(256) void k_transform_b(const u16* __restrict__ x,
    const u16* __restrict__ Wt, const u16* __restrict__ bt, const int* __restrict__ flag,
    float* __restrict__ t, float* __restrict__ s1, float* __restrict__ s2){
  if (flag[0] == 0) return;
  __shared__ float sW[NF*NH];     // 32 KB, f32-converted weights [k][c]
  __shared__ u16 sX[64*136];      // staged x tile, row stride 136 (16B-aligned)
  int tid = threadIdx.x;
  for (int i = tid*8; i < NF*NH; i += 2048){
    cv8(*(const uint4*)(Wt + i), &sW[i]);
  }
  int node0 = blockIdx.x*64;
  int nrows = min(64, NN - node0);
  for (int i = tid; i < 1024; i += 256){     // 64 rows x 16 groups of 8 cols
    int r = i >> 4, c8 = i & 15;
    uint4 q;
    if (r < nrows) q = *(const uint4*)(x + (size_t)(node0+r)*NF + c8*8);
    else { q.x=0; q.y=0; q.z=0; q.w=0; }
    *(uint4*)&sX[r*136 + c8*8] = q;
  }
  __syncthreads();
  int lane = tid & 63, w = tid >> 6, c0 = w*16;
  float acc[16];
  #pragma unroll
  for (int cc = 0; cc < 16; cc++) acc[cc] = bf1(bt[c0+cc]);
  for (int k2 = 0; k2 < 64; k2++){
    u32 p = *(const u32*)&sX[lane*136 + k2*2];
    float u0 = bflo(p), u1 = bfhi(p);
    const float4* w0 = (const float4*)&sW[(2*k2)*NH + c0];
    const float4* w1 = (const float4*)&sW[(2*k2+1)*NH + c0];
    float4 a0=w0[0], a1=w0[1], a2=w0[2], a3=w0[3];
    float4 b0=w1[0], b1=w1[1], b2=w1[2], b3=w1[3];
    acc[0]+=u0*a0.x+u1*b0.x; acc[1]+=u0*a0.y+u1*b0.y; acc[2]+=u0*a0.z+u1*b0.z; acc[3]+=u0*a0.w+u1*b0.w;
    acc[4]+=u0*a1.x+u1*b1.x; acc[5]+=u0*a1.y+u1*b1.y; acc[6]+=u0*a1.z+u1*b1.z; acc[7]+=u0*a1.w+u1*b1.w;
    acc[8]+=u0*a2.x+u1*b2.x; acc[9]+=u0*a2.y+u1*b2.y; acc[10]+=u0*a2.z+u1*b2.z; acc[11]+=u0*a2.w+u1*b2.w;
    acc[12]+=u0*a3.x+u1*b3.x; acc[13]+=u0*a3.y+u1*b3.y; acc[14]+=u0*a3.z+u1*b3.z; acc[15]+=u0*a3.w+u1*b3.w;
  }
  bool ok = (lane < nrows);
  if (ok){
    float* dst = &t[(size_t)(node0+lane)*NH + c0];
    #pragma unroll
    for (int q4 = 0; q4 < 4; q4++){
      float4 v; v.x=acc[q4*4]; v.y=acc[q4*4+1]; v.z=acc[q4*4+2]; v.w=acc[q4*4+3];
      *(float4*)&dst[q4*4] = v;
    }
  }
  #pragma unroll
  for (int cc = 0; cc < 16; cc++){
    float v = ok ? acc[cc] : 0.f;
    float v2 = v*v;
    #pragma unroll
    for (int m = 1; m < 64; m <<= 1){ v += __shfl_xor(v, m); v2 += __shfl_xor(v2, m); }
    if (lane == 0){
      unsafeAtomicAdd(&s1[c0+cc], v);
      unsafeAtomicAdd(&s2[c0+cc], v2);
    }
  }
}

// ---- transform (f32 fallback, old structure)
__global__ __launch_bounds__(256) void k_transform_f(const float* __restrict__ x,
    const float* __restrict__ Wt, const float* __restrict__ bt, const int* __restrict__ flag,
    float* __restrict__ t, float* __restrict__ s1, float* __restrict__ s2){
  if (flag[0] != 0) return;
  __shared__ float sW[NF*NH];
  __shared__ float sRed[8*NH];
  int tid = threadIdx.x;
  for (int i = tid*4; i < NF*NH; i += 1024)
    *(float4*)&sW[i] = *(const float4*)(Wt + i);
  __syncthreads();
  int tx = tid & 63, ty = tid >> 6;
  int row0 = blockIdx.x*64 + ty*16;
  float b = bt[tx];
  float ls1 = 0.f, ls2 = 0.f;
  for (int i = 0; i < 16; i++){
    int row = row0 + i;
    if (row >= NN) break;
    const float4* xr = (const float4*)(x + (size_t)row*NF);
    float acc = b;
    #pragma unroll
    for (int k4 = 0; k4 < 32; k4++){
      float4 f = xr[k4];
      int kb = k4*4;
      acc += f.x*sW[(kb+0)*NH+tx];
      acc += f.y*sW[(kb+1)*NH+tx];
      acc += f.z*sW[(kb+2)*NH+tx];
      acc += f.w*sW[(kb+3)*NH+tx];
    }
    t[(size_t)row*NH + tx] = acc;
    ls1 += acc; ls2 += acc*acc;
  }
  sRed[ty*NH + tx] = ls1;
  sRed[(4+ty)*NH + tx] = ls2;
  __syncthreads();
  if (ty == 0){
    float a1 = sRed[tx] + sRed[NH+tx] + sRed[2*NH+tx] + sRed[3*NH+tx];
    float a2 = sRed[4*NH+tx] + sRed[5*NH+tx] + sRed[6*NH+tx] + sRed[7*NH+tx];
    unsafeAtomicAdd(&s1[tx], a1);
    unsafeAtomicAdd(&s2[tx], a2);
  }
}

// ---- fold BN
__global__ void k_bnfinal(const float* __restrict__ s1, const float* __restrict__ s2,
    const void* __restrict__ gamma, const void* __restrict__ beta, int ofs,
    const int* __restrict__ flag, float* __restrict__ scA, float* __restrict__ shB){
  int c = threadIdx.x;
  int bf = flag[0];
  float g  = bf ? bf1(((const u16*)gamma)[ofs+c]) : ((const float*)gamma)[ofs+c];
  float be = bf ? bf1(((const u16*)beta)[ofs+c])  : ((const float*)beta)[ofs+c];
  float mean = s1[c] * (1.f/NN);
  float var  = s2[c] * (1.f/NN) - mean*mean;
  float r = rsqrtf(fmaxf(var, 0.f) + 1e-5f);
  float sc = g * r;
  scA[c] = sc;
  shB[c] = be - mean*sc;
}

// ---- per-graph embed
__global__ __launch_bounds__(256) void k_embed(const float* __restrict__ t,
    const float* __restrict__ scA, const float* __restrict__ shB,
    float* __restrict__ h, const int* __restrict__ starts, const int* __restrict__ flag,
    void* __restrict__ dout, int layer){
  __shared__ float sRed[8*NH];
  int g = blockIdx.x;
  int tx = threadIdx.x & 63, ty = threadIdx.x >> 6;
  int st = starts[g], en = starts[g+1];
  float sc = scA[tx], sh = shB[tx];
  float ls1 = 0.f, ls2 = 0.f;
  for (int n = st + ty; n < en; n += 4){
    float z = t[(size_t)n*NH + tx] * sc + sh;
    h[(size_t)n*NH + tx] = z;
    ls1 += z; ls2 += z*z;
  }
  sRed[ty*NH + tx] = ls1;
  sRed[(4+ty)*NH + tx] = ls2;
  __syncthreads();
  if (ty == 0){
    float a1 = sRed[tx] + sRed[NH+tx] + sRed[2*NH+tx] + sRed[3*NH+tx];
    float a2 = sRed[4*NH+tx] + sRed[5*NH+tx] + sRed[6*NH+tx] + sRed[7*NH+tx];
    int cnt = en - st;
    float inv = 1.f / (float)max(cnt, 1);
    float m = a1 * inv;
    float var = a2 * inv - m*m;
    float s = sqrtf(fmaxf(var, 0.f));
    size_t eidx = ((size_t)layer*NG + g)*NH + tx;
    size_t sidx = (size_t)4*NG*NH + eidx;
    if (flag[0]){
      ((__hip_bfloat16*)dout)[eidx] = __float2bfloat16(m);
      ((__hip_bfloat16*)dout)[sidx] = __float2bfloat16(s);
    } else {
      ((float*)dout)[eidx] = m;
      ((float*)dout)[sidx] = s;
    }
  }
}

// ---- MLP (bf16 fast path): in-place t = relu(relu(U@W1)@W2) over U; stats.
__global__ __launch_bounds__(256) void k_mlp_b(float* __restrict__ U,
    const u16* __restrict__ W1, const u16* __restrict__ W2, int wofs,
    const int* __restrict__ flag, float* __restrict__ s1, float* __restrict__ s2){
  if (flag[0] == 0) return;
  __shared__ float sW1[NH*NH];   // 16 KB
  __shared__ float sW2[NH*NH];   // 16 KB
  __shared__ float sU[64*65];    // 16.6 KB, +1 pad: conflict-free lane-row reads
  int tid = threadIdx.x;
  for (int i = tid*8; i < NH*NH; i += 2048){
    cv8(*(const uint4*)(W1 + wofs + i), &sW1[i]);
    cv8(*(const uint4*)(W2 + wofs + i), &sW2[i]);
  }
  int node0 = blockIdx.x*64;
  int nrows = min(64, NN - node0);
  for (int i = tid; i < 1024; i += 256){     // 64 rows x 16 float4 groups
    int r = i >> 4, c4 = i & 15;
    float4 q;
    if (r < nrows) q = *(const float4*)&U[(size_t)(node0+r)*NH + c4*4];
    else { q.x=0.f; q.y=0.f; q.z=0.f; q.w=0.f; }
    float* d = &sU[r*65 + c4*4];
    d[0]=q.x; d[1]=q.y; d[2]=q.z; d[3]=q.w;
  }
  __syncthreads();
  int lane = tid & 63, w = tid >> 6, c0 = w*16;
  float va[16];
  #pragma unroll
  for (int cc = 0; cc < 16; cc++) va[cc] = 0.f;
  for (int k = 0; k < 64; k++){
    float u = sU[lane*65 + k];
    const float4* wr = (const float4*)&sW1[k*NH + c0];
    float4 a0=wr[0], a1=wr[1], a2=wr[2], a3=wr[3];
    va[0]+=u*a0.x; va[1]+=u*a0.y; va[2]+=u*a0.z; va[3]+=u*a0.w;
    va[4]+=u*a1.x; va[5]+=u*a1.y; va[6]+=u*a1.z; va[7]+=u*a1.w;
    va[8]+=u*a2.x; va[9]+=u*a2.y; va[10]+=u*a2.z; va[11]+=u*a2.w;
    va[12]+=u*a3.x; va[13]+=u*a3.y; va[14]+=u*a3.z; va[15]+=u*a3.w;
  }
  __syncthreads();
  #pragma unroll
  for (int cc = 0; cc < 16; cc++) sU[lane*65 + c0 + cc] = fmaxf(va[cc], 0.f);
  __syncthreads();
  #pragma unroll
  for (int cc = 0; cc < 16; cc++) va[cc] = 0.f;
  for (int k = 0; k < 64; k++){
    float u = sU[lane*65 + k];
    const float4* wr = (const float4*)&sW2[k*NH + c0];
    float4 a0=wr[0], a1=wr[1], a2=wr[2], a3=wr[3];
    va[0]+=u*a0.x; va[1]+=u*a0.y; va[2]+=u*a0.z; va[3]+=u*a0.w;
    va[4]+=u*a1.x; va[5]+=u*a1.y; va[6]+=u*a1.z; va[7]+=u*a1.w;
    va[8]+=u*a2.x; va[9]+=u*a2.y; va[10]+=u*a2.z; va[11]+=u*a2.w;
    va[12]+=u*a3.x; va[13]+=u*a3.y; va[14]+=u*a3.z; va[15]+=u*a3.w;
  }
  #pragma unroll
  for (int cc = 0; cc < 16; cc++) va[cc] = fmaxf(va[cc], 0.f);
  bool ok = (lane < nrows);
  if (ok){
    float* dst = &U[(size_t)(node0+lane)*NH + c0];
    #pragma unroll
    for (int q4 = 0; q4 < 4; q4++){
      float4 v; v.x=va[q4*4]; v.y=va[q4*4+1]; v.z=va[q4*4+2]; v.w=va[q4*4+3];
      *(float4*)&dst[q4*4] = v;
    }
  }
  #pragma unroll
  for (int cc = 0; cc < 16; cc++){
    float v = va[cc];            // pad rows produce exact 0 -> no mask needed
    float v2 = v*v;
    #pragma unroll
    for (int m = 1; m < 64; m <<= 1){ v += __shfl_xor(v, m); v2 += __shfl_xor(v2, m); }
    if (lane == 0){
      unsafeAtomicAdd(&s1[c0+cc], v);
      unsafeAtomicAdd(&s2[c0+cc], v2);
    }
  }
}

// ---- MLP (f32 fallback): old broadcast structure, U from global, in-place
__global__ __launch_bounds__(256) void k_mlp_f(float* __restrict__ U,
    const float* __restrict__ W1, const float* __restrict__ W2, int wofs,
    const int* __restrict__ flag, float* __restrict__ s1, float* __restrict__ s2){
  if (flag[0] != 0) return;
  __shared__ float sU[64*NH];
  __shared__ float sV[64*NH];
  __shared__ float sW1[NH*NH];
  __shared__ float sW2[NH*NH];
  int tid = threadIdx.x;
  for (int i = tid*4; i < NH*NH; i += 1024){
    *(float4*)&sW1[i] = *(const float4*)(W1 + wofs + i);
    *(float4*)&sW2[i] = *(const float4*)(W2 + wofs + i);
  }
  int node0 = blockIdx.x*64;
  int nrows = min(64, NN - node0);
  for (int i = tid*4; i < nrows*NH; i += 1024)
    *(float4*)&sU[i] = *(const float4*)&U[(size_t)node0*NH + i];
  __syncthreads();
  int tx = tid & 63, ty = tid >> 6;
  for (int i = 0; i < 16; i++){
    int row = ty*16 + i;
    if (row >= nrows) break;
    const float4* ur = (const float4*)&sU[row*NH];
    float acc = 0.f;
    #pragma unroll
    for (int k4 = 0; k4 < 16; k4++){
      float4 u = ur[k4];
      acc += u.x*sW1[(k4*4+0)*NH+tx];
      acc += u.y*sW1[(k4*4+1)*NH+tx];
      acc += u.z*sW1[(k4*4+2)*NH+tx];
      acc += u.w*sW1[(k4*4+3)*NH+tx];
    }
    sV[row*NH + tx] = fmaxf(acc, 0.f);
  }
  __syncthreads();
  float ls1 = 0.f, ls2 = 0.f;
  for (int i = 0; i < 16; i++){
    int row = ty*16 + i;
    if (row >= nrows) break;
    const float4* vr = (const float4*)&sV[row*NH];
    float acc = 0.f;
    #pragma unroll
    for (int k4 = 0; k4 < 16; k4++){
      float4 v = vr[k4];
      acc += v.x*sW2[(k4*4+0)*NH+tx];
      acc += v.y*sW2[(k4*4+1)*NH+tx];
      acc += v.z*sW2[(k4*4+2)*NH+tx];
      acc += v.w*sW2[(k4*4+3)*NH+tx];
    }
    float tv = fmaxf(acc, 0.f);
    U[(size_t)node0*NH + row*NH + tx] = tv;
    ls1 += tv; ls2 += tv*tv;
  }
  __syncthreads();
  sW1[ty*NH + tx] = ls1;
  sW1[(4+ty)*NH + tx] = ls2;
  __syncthreads();
  if (ty == 0){
    float a1 = sW1[tx] + sW1[NH+tx] + sW1[2*NH+tx] + sW1[3*NH+tx];
    float a2 = sW1[4*NH+tx] + sW1[5*NH+tx] + sW1[6*NH+tx] + sW1[7*NH+tx];
    unsafeAtomicAdd(&s1[tx], a1);
    unsafeAtomicAdd(&s2[tx], a2);
  }
}

extern "C" void kernel_launch(void* const* d_in, const int* in_sizes, int n_in,
                              void* d_out, int out_size, void* d_ws, size_t ws_size,
                              hipStream_t stream) {
  const void* x    = d_in[0];
  const int* ei    = (const int*)d_in[1];
  const int* batch = (const int*)d_in[2];
  const void* Wt   = d_in[3];
  const void* bt   = d_in[4];
  const void* g0   = d_in[5];
  const void* b0   = d_in[6];
  const void* W1   = d_in[7];
  const void* W2   = d_in[8];
  const void* gs   = d_in[9];
  const void* bs   = d_in[10];

  float* hbuf = (float*)d_ws;           // NN*NH f32
  float* ubuf = hbuf + (size_t)NN*NH;   // NN*NH f32 (U, then in-place T)
  float* s1   = ubuf + (size_t)NN*NH;   // 64
  float* s2   = s1 + NH;                // 64
  float* scA  = s2 + NH;                // 64
  float* shB  = scA + NH;               // 64
  int* starts = (int*)(shB + NH);       // 512
  int* flag   = starts + 512;           // 64 (padded)
  int* deg    = flag + 64;              // NN
  int* rowptr = deg + NN;               // NN+64
  int* cursor = rowptr + NN + 64;       // NN
  int* csr    = cursor + NN;            // NE

  hipMemsetAsync(s1, 0, 2*NH*sizeof(float), stream);
  hipMemsetAsync(deg, 0, NN*sizeof(int), stream);
  k_detect<<<1, 64, 0, stream>>>((const u32*)x, flag);
  k_bounds<<<1, 512, 0, stream>>>(batch, starts);
  k_count<<<(NE+255)/256, 256, 0, stream>>>(ei, deg);
  k_scan<<<1, 1024, 0, stream>>>(deg, rowptr, cursor);
  k_fill<<<(NE+255)/256, 256, 0, stream>>>(ei, cursor, csr);

  k_transform_b<<<(NN+63)/64, 256, 0, stream>>>((const u16*)x, (const u16*)Wt, (const u16*)bt, flag, ubuf, s1, s2);
  k_transform_f<<<(NN+63)/64, 256, 0, stream>>>((const float*)x, (const float*)Wt, (const float*)bt, flag, ubuf, s1, s2);
  k_bnfinal<<<1, NH, 0, stream>>>(s1, s2, g0, b0, 0, flag, scA, shB);
  k_embed<<<NG, 256, 0, stream>>>(ubuf, scA, shB, hbuf, starts, flag, d_out, 0);

  for (int l = 0; l < 3; l++){
    hipMemsetAsync(s1, 0, 2*NH*sizeof(float), stream);
    k_gather<<<(NN+3)/4, 256, 0, stream>>>(hbuf, rowptr, csr, ubuf);
    k_mlp_b<<<(NN+63)/64, 256, 0, stream>>>(ubuf, (const u16*)W1, (const u16*)W2, l*NH*NH, flag, s1, s2);
    k_mlp_f<<<(NN+63)/64, 256, 0, stream>>>(ubuf, (const float*)W1, (const float*)W2, l*NH*NH, flag, s1, s2);
    k_bnfinal<<<1, NH, 0, stream>>>(s1, s2, gs, bs, l*NH, flag, scA, shB);
    k_embed<<<NG, 256, 0, stream>>>(ubuf, scA, shB, hbuf, starts, flag, d_out, l+1);
  }
}

// Round 5
// 581.068 us; speedup vs baseline: 4.2355x; 1.1853x over previous
//
#include <hip/hip_runtime.h>
#include <hip/hip_bf16.h>

#define NN 50000
#define NE 800000
#define NG 500
#define NF 128
#define NH 64
#define SCAN_B ((NN + 255)/256)   // 196

typedef unsigned int u32;
typedef unsigned short u16;

__device__ __forceinline__ float bflo(u32 p){ return __uint_as_float(p << 16); }
__device__ __forceinline__ float bfhi(u32 p){ return __uint_as_float(p & 0xffff0000u); }
__device__ __forceinline__ float bf1(u16 v){ return __uint_as_float(((u32)v) << 16); }

__device__ __forceinline__ void cv8(uint4 q, float* dst){
  dst[0]=bflo(q.x); dst[1]=bfhi(q.x);
  dst[2]=bflo(q.y); dst[3]=bfhi(q.y);
  dst[4]=bflo(q.z); dst[5]=bfhi(q.z);
  dst[6]=bflo(q.w); dst[7]=bfhi(q.w);
}

// ---- dtype probe
__global__ void k_detect(const u32* __restrict__ x, int* __restrict__ flag){
  int lane = threadIdx.x;
  u32 w = x[lane];
  u32 lo = w & 0xFFFFu;
  u32 e = (lo >> 7) & 0xFFu;
  bool vote = (e >= 0x60u && e <= 0x8Fu);
  unsigned long long m = __ballot(vote);
  if (lane == 0) flag[0] = (__popcll(m) >= 32) ? 1 : 0;
}

// ---- graph boundaries
__global__ void k_bounds(const int* __restrict__ batch, int* __restrict__ starts){
  int g = threadIdx.x;
  if (g > NG) return;
  int lo = 0, hi = NN;
  while (lo < hi){ int mid = (lo + hi) >> 1; if (batch[mid] < g) lo = mid + 1; else hi = mid; }
  starts[g] = lo;
}

// ---- CSR build: degree count
__global__ __launch_bounds__(256) void k_count(const int* __restrict__ ei, int* __restrict__ deg){
  int e = blockIdx.x*256 + threadIdx.x;
  if (e >= NE) return;
  atomicAdd(&deg[ei[NE + e]], 1);
}

// ---- hierarchical coalesced scan (3 phases), replaces serial 1-block scan
__global__ __launch_bounds__(256) void k_scanA(const int* __restrict__ deg, int* __restrict__ bsum){
  __shared__ int red[256];
  int t = threadIdx.x;
  int i = blockIdx.x*256 + t;
  red[t] = (i < NN) ? deg[i] : 0;
  __syncthreads();
  for (int off = 128; off > 0; off >>= 1){
    if (t < off) red[t] += red[t+off];
    __syncthreads();
  }
  if (t == 0) bsum[blockIdx.x] = red[0];
}

__global__ __launch_bounds__(256) void k_scanB(int* __restrict__ bsum){
  __shared__ int part[256];
  int t = threadIdx.x;
  int v = (t < SCAN_B) ? bsum[t] : 0;
  part[t] = v;
  __syncthreads();
  for (int off = 1; off < 256; off <<= 1){
    int u = (t >= off) ? part[t-off] : 0;
    __syncthreads();
    part[t] += u;
    __syncthreads();
  }
  if (t < SCAN_B) bsum[t] = part[t] - v;   // exclusive
}

__global__ __launch_bounds__(256) void k_scanC(const int* __restrict__ deg, const int* __restrict__ bsum,
    int* __restrict__ rowptr, int* __restrict__ cursor){
  __shared__ int part[256];
  int t = threadIdx.x;
  int i = blockIdx.x*256 + t;
  int v = (i < NN) ? deg[i] : 0;
  part[t] = v;
  __syncthreads();
  for (int off = 1; off < 256; off <<= 1){
    int u = (t >= off) ? part[t-off] : 0;
    __syncthreads();
    part[t] += u;
    __syncthreads();
  }
  int ex = part[t] - v + bsum[blockIdx.x];
  if (i < NN){ rowptr[i] = ex; cursor[i] = ex; }
  if (blockIdx.x == 0 && t == 0) rowptr[NN] = NE;
}

// ---- CSR fill
__global__ __launch_bounds__(256) void k_fill(const int* __restrict__ ei,
    int* __restrict__ cursor, int* __restrict__ csr){
  int e = blockIdx.x*256 + threadIdx.x;
  if (e >= NE) return;
  int dst = ei[NE + e];
  int slot = atomicAdd(&cursor[dst], 1);
  csr[slot] = ei[e];
}

// ---- gather: U[node] = h[node] + sum_{src} h[src]  (one wave per node, no LDS)
__global__ __launch_bounds__(256) void k_gather(const float* __restrict__ h,
    const int* __restrict__ rowptr, const int* __restrict__ csr, float* __restrict__ U){
  int wid = threadIdx.x >> 6, lane = threadIdx.x & 63;
  int node = blockIdx.x*4 + wid;
  if (node >= NN) return;
  int chunk = lane & 15, epar = lane >> 4;
  int beg = rowptr[node], en = rowptr[node+1];
  float4 acc;
  if (epar == 0) acc = *(const float4*)&h[(size_t)node*NH + chunk*4];
  else { acc.x=0.f; acc.y=0.f; acc.z=0.f; acc.w=0.f; }
  for (int j = beg + epar; j < en; j += 4){
    int src = csr[j];
    float4 v = *(const float4*)&h[(size_t)src*NH + chunk*4];
    acc.x += v.x; acc.y += v.y; acc.z += v.z; acc.w += v.w;
  }
  acc.x += __shfl_xor(acc.x, 16); acc.y += __shfl_xor(acc.y, 16);
  acc.z += __shfl_xor(acc.z, 16); acc.w += __shfl_xor(acc.w, 16);
  acc.x += __shfl_xor(acc.x, 32); acc.y += __shfl_xor(acc.y, 32);
  acc.z += __shfl_xor(acc.z, 32); acc.w += __shfl_xor(acc.w, 32);
  if (epar == 0) *(float4*)&U[(size_t)node*NH + chunk*4] = acc;
}

// ---- transform (bf16 fast path): t = x@Wt + bt; stats. lane=row, wave=16 cols.
__global__ __launch_bounds__(256) void k_transform_b(const u16* __restrict__ x,
    const u16* __restrict__ Wt, const u16* __restrict__ bt, const int* __restrict__ flag,
    float* __restrict__ t, float* __restrict__ s1, float* __restrict__ s2){
  if (flag[0] == 0) return;
  __shared__ float sW[NF*NH];     // 32 KB
  __shared__ u16 sX[64*136];      // staged x tile
  int tid = threadIdx.x;
  for (int i = tid*8; i < NF*NH; i += 2048){
    cv8(*(const uint4*)(Wt + i), &sW[i]);
  }
  int node0 = blockIdx.x*64;
  int nrows = min(64, NN - node0);
  for (int i = tid; i < 1024; i += 256){
    int r = i >> 4, c8 = i & 15;
    uint4 q;
    if (r < nrows) q = *(const uint4*)(x + (size_t)(node0+r)*NF + c8*8);
    else { q.x=0; q.y=0; q.z=0; q.w=0; }
    *(uint4*)&sX[r*136 + c8*8] = q;
  }
  __syncthreads();
  int lane = tid & 63, w = tid >> 6, c0 = w*16;
  float acc[16];
  #pragma unroll
  for (int cc = 0; cc < 16; cc++) acc[cc] = bf1(bt[c0+cc]);
  for (int k2 = 0; k2 < 64; k2++){
    u32 p = *(const u32*)&sX[lane*136 + k2*2];
    float u0 = bflo(p), u1 = bfhi(p);
    const float4* w0 = (const float4*)&sW[(2*k2)*NH + c0];
    const float4* w1 = (const float4*)&sW[(2*k2+1)*NH + c0];
    float4 a0=w0[0], a1=w0[1], a2=w0[2], a3=w0[3];
    float4 b0=w1[0], b1=w1[1], b2=w1[2], b3=w1[3];
    acc[0]+=u0*a0.x+u1*b0.x; acc[1]+=u0*a0.y+u1*b0.y; acc[2]+=u0*a0.z+u1*b0.z; acc[3]+=u0*a0.w+u1*b0.w;
    acc[4]+=u0*a1.x+u1*b1.x; acc[5]+=u0*a1.y+u1*b1.y; acc[6]+=u0*a1.z+u1*b1.z; acc[7]+=u0*a1.w+u1*b1.w;
    acc[8]+=u0*a2.x+u1*b2.x; acc[9]+=u0*a2.y+u1*b2.y; acc[10]+=u0*a2.z+u1*b2.z; acc[11]+=u0*a2.w+u1*b2.w;
    acc[12]+=u0*a3.x+u1*b3.x; acc[13]+=u0*a3.y+u1*b3.y; acc[14]+=u0*a3.z+u1*b3.z; acc[15]+=u0*a3.w+u1*b3.w;
  }
  bool ok = (lane < nrows);
  if (ok){
    float* dst = &t[(size_t)(node0+lane)*NH + c0];
    #pragma unroll
    for (int q4 = 0; q4 < 4; q4++){
      float4 v; v.x=acc[q4*4]; v.y=acc[q4*4+1]; v.z=acc[q4*4+2]; v.w=acc[q4*4+3];
      *(float4*)&dst[q4*4] = v;
    }
  }
  #pragma unroll
  for (int cc = 0; cc < 16; cc++){
    float v = ok ? acc[cc] : 0.f;
    float v2 = v*v;
    #pragma unroll
    for (int m = 1; m < 64; m <<= 1){ v += __shfl_xor(v, m); v2 += __shfl_xor(v2, m); }
    if (lane == 0){
      unsafeAtomicAdd(&s1[c0+cc], v);
      unsafeAtomicAdd(&s2[c0+cc], v2);
    }
  }
}

// ---- transform (f32 fallback)
__global__ __launch_bounds__(256) void k_transform_f(const float* __restrict__ x,
    const float* __restrict__ Wt, const float* __restrict__ bt, const int* __restrict__ flag,
    float* __restrict__ t, float* __restrict__ s1, float* __restrict__ s2){
  if (flag[0] != 0) return;
  __shared__ float sW[NF*NH];
  __shared__ float sRed[8*NH];
  int tid = threadIdx.x;
  for (int i = tid*4; i < NF*NH; i += 1024)
    *(float4*)&sW[i] = *(const float4*)(Wt + i);
  __syncthreads();
  int tx = tid & 63, ty = tid >> 6;
  int row0 = blockIdx.x*64 + ty*16;
  float b = bt[tx];
  float ls1 = 0.f, ls2 = 0.f;
  for (int i = 0; i < 16; i++){
    int row = row0 + i;
    if (row >= NN) break;
    const float4* xr = (const float4*)(x + (size_t)row*NF);
    float acc = b;
    #pragma unroll
    for (int k4 = 0; k4 < 32; k4++){
      float4 f = xr[k4];
      int kb = k4*4;
      acc += f.x*sW[(kb+0)*NH+tx];
      acc += f.y*sW[(kb+1)*NH+tx];
      acc += f.z*sW[(kb+2)*NH+tx];
      acc += f.w*sW[(kb+3)*NH+tx];
    }
    t[(size_t)row*NH + tx] = acc;
    ls1 += acc; ls2 += acc*acc;
  }
  sRed[ty*NH + tx] = ls1;
  sRed[(4+ty)*NH + tx] = ls2;
  __syncthreads();
  if (ty == 0){
    float a1 = sRed[tx] + sRed[NH+tx] + sRed[2*NH+tx] + sRed[3*NH+tx];
    float a2 = sRed[4*NH+tx] + sRed[5*NH+tx] + sRed[6*NH+tx] + sRed[7*NH+tx];
    unsafeAtomicAdd(&s1[tx], a1);
    unsafeAtomicAdd(&s2[tx], a2);
  }
}

// ---- fold BN (and re-zero s1/s2 for the next layer's accumulation)
__global__ void k_bnfinal(float* __restrict__ s1, float* __restrict__ s2,
    const void* __restrict__ gamma, const void* __restrict__ beta, int ofs,
    const int* __restrict__ flag, float* __restrict__ scA, float* __restrict__ shB){
  int c = threadIdx.x;
  int bf = flag[0];
  float g  = bf ? bf1(((const u16*)gamma)[ofs+c]) : ((const float*)gamma)[ofs+c];
  float be = bf ? bf1(((const u16*)beta)[ofs+c])  : ((const float*)beta)[ofs+c];
  float mean = s1[c] * (1.f/NN);
  float var  = s2[c] * (1.f/NN) - mean*mean;
  float r = rsqrtf(fmaxf(var, 0.f) + 1e-5f);
  float sc = g * r;
  scA[c] = sc;
  shB[c] = be - mean*sc;
  s1[c] = 0.f;   // ready for next layer (consumed this layer's stats already)
  s2[c] = 0.f;
}

// ---- per-graph embed
__global__ __launch_bounds__(256) void k_embed(const float* __restrict__ t,
    const float* __restrict__ scA, const float* __restrict__ shB,
    float* __restrict__ h, const int* __restrict__ starts, const int* __restrict__ flag,
    void* __restrict__ dout, int layer){
  __shared__ float sRed[8*NH];
  int g = blockIdx.x;
  int tx = threadIdx.x & 63, ty = threadIdx.x >> 6;
  int st = starts[g], en = starts[g+1];
  float sc = scA[tx], sh = shB[tx];
  float ls1 = 0.f, ls2 = 0.f;
  for (int n = st + ty; n < en; n += 4){
    float z = t[(size_t)n*NH + tx] * sc + sh;
    h[(size_t)n*NH + tx] = z;
    ls1 += z; ls2 += z*z;
  }
  sRed[ty*NH + tx] = ls1;
  sRed[(4+ty)*NH + tx] = ls2;
  __syncthreads();
  if (ty == 0){
    float a1 = sRed[tx] + sRed[NH+tx] + sRed[2*NH+tx] + sRed[3*NH+tx];
    float a2 = sRed[4*NH+tx] + sRed[5*NH+tx] + sRed[6*NH+tx] + sRed[7*NH+tx];
    int cnt = en - st;
    float inv = 1.f / (float)max(cnt, 1);
    float m = a1 * inv;
    float var = a2 * inv - m*m;
    float s = sqrtf(fmaxf(var, 0.f));
    size_t eidx = ((size_t)layer*NG + g)*NH + tx;
    size_t sidx = (size_t)4*NG*NH + eidx;
    if (flag[0]){
      ((__hip_bfloat16*)dout)[eidx] = __float2bfloat16(m);
      ((__hip_bfloat16*)dout)[sidx] = __float2bfloat16(s);
    } else {
      ((float*)dout)[eidx] = m;
      ((float*)dout)[sidx] = s;
    }
  }
}

// ---- MLP (bf16 fast path): in-place t = relu(relu(U@W1)@W2) over U; stats.
__global__ __launch_bounds__(256) void k_mlp_b(float* __restrict__ U,
    const u16* __restrict__ W1, const u16* __restrict__ W2, int wofs,
    const int* __restrict__ flag, float* __restrict__ s1, float* __restrict__ s2){
  if (flag[0] == 0) return;
  __shared__ float sW1[NH*NH];
  __shared__ float sW2[NH*NH];
  __shared__ float sU[64*65];
  int tid = threadIdx.x;
  for (int i = tid*8; i < NH*NH; i += 2048){
    cv8(*(const uint4*)(W1 + wofs + i), &sW1[i]);
    cv8(*(const uint4*)(W2 + wofs + i), &sW2[i]);
  }
  int node0 = blockIdx.x*64;
  int nrows = min(64, NN - node0);
  for (int i = tid; i < 1024; i += 256){
    int r = i >> 4, c4 = i & 15;
    float4 q;
    if (r < nrows) q = *(const float4*)&U[(size_t)(node0+r)*NH + c4*4];
    else { q.x=0.f; q.y=0.f; q.z=0.f; q.w=0.f; }
    float* d = &sU[r*65 + c4*4];
    d[0]=q.x; d[1]=q.y; d[2]=q.z; d[3]=q.w;
  }
  __syncthreads();
  int lane = tid & 63, w = tid >> 6, c0 = w*16;
  float va[16];
  #pragma unroll
  for (int cc = 0; cc < 16; cc++) va[cc] = 0.f;
  for (int k = 0; k < 64; k++){
    float u = sU[lane*65 + k];
    const float4* wr = (const float4*)&sW1[k*NH + c0];
    float4 a0=wr[0], a1=wr[1], a2=wr[2], a3=wr[3];
    va[0]+=u*a0.x; va[1]+=u*a0.y; va[2]+=u*a0.z; va[3]+=u*a0.w;
    va[4]+=u*a1.x; va[5]+=u*a1.y; va[6]+=u*a1.z; va[7]+=u*a1.w;
    va[8]+=u*a2.x; va[9]+=u*a2.y; va[10]+=u*a2.z; va[11]+=u*a2.w;
    va[12]+=u*a3.x; va[13]+=u*a3.y; va[14]+=u*a3.z; va[15]+=u*a3.w;
  }
  __syncthreads();
  #pragma unroll
  for (int cc = 0; cc < 16; cc++) sU[lane*65 + c0 + cc] = fmaxf(va[cc], 0.f);
  __syncthreads();
  #pragma unroll
  for (int cc = 0; cc < 16; cc++) va[cc] = 0.f;
  for (int k = 0; k < 64; k++){
    float u = sU[lane*65 + k];
    const float4* wr = (const float4*)&sW2[k*NH + c0];
    float4 a0=wr[0], a1=wr[1], a2=wr[2], a3=wr[3];
    va[0]+=u*a0.x; va[1]+=u*a0.y; va[2]+=u*a0.z; va[3]+=u*a0.w;
    va[4]+=u*a1.x; va[5]+=u*a1.y; va[6]+=u*a1.z; va[7]+=u*a1.w;
    va[8]+=u*a2.x; va[9]+=u*a2.y; va[10]+=u*a2.z; va[11]+=u*a2.w;
    va[12]+=u*a3.x; va[13]+=u*a3.y; va[14]+=u*a3.z; va[15]+=u*a3.w;
  }
  #pragma unroll
  for (int cc = 0; cc < 16; cc++) va[cc] = fmaxf(va[cc], 0.f);
  bool ok = (lane < nrows);
  if (ok){
    float* dst = &U[(size_t)(node0+lane)*NH + c0];
    #pragma unroll
    for (int q4 = 0; q4 < 4; q4++){
      float4 v; v.x=va[q4*4]; v.y=va[q4*4+1]; v.z=va[q4*4+2]; v.w=va[q4*4+3];
      *(float4*)&dst[q4*4] = v;
    }
  }
  #pragma unroll
  for (int cc = 0; cc < 16; cc++){
    float v = va[cc];
    float v2 = v*v;
    #pragma unroll
    for (int m = 1; m < 64; m <<= 1){ v += __shfl_xor(v, m); v2 += __shfl_xor(v2, m); }
    if (lane == 0){
      unsafeAtomicAdd(&s1[c0+cc], v);
      unsafeAtomicAdd(&s2[c0+cc], v2);
    }
  }
}

// ---- MLP (f32 fallback)
__global__ __launch_bounds__(256) void k_mlp_f(float* __restrict__ U,
    const float* __restrict__ W1, const float* __restrict__ W2, int wofs,
    const int* __restrict__ flag, float* __restrict__ s1, float* __restrict__ s2){
  if (flag[0] != 0) return;
  __shared__ float sU[64*NH];
  __shared__ float sV[64*NH];
  __shared__ float sW1[NH*NH];
  __shared__ float sW2[NH*NH];
  int tid = threadIdx.x;
  for (int i = tid*4; i < NH*NH; i += 1024){
    *(float4*)&sW1[i] = *(const float4*)(W1 + wofs + i);
    *(float4*)&sW2[i] = *(const float4*)(W2 + wofs + i);
  }
  int node0 = blockIdx.x*64;
  int nrows = min(64, NN - node0);
  for (int i = tid*4; i < nrows*NH; i += 1024)
    *(float4*)&sU[i] = *(const float4*)&U[(size_t)node0*NH + i];
  __syncthreads();
  int tx = tid & 63, ty = tid >> 6;
  for (int i = 0; i < 16; i++){
    int row = ty*16 + i;
    if (row >= nrows) break;
    const float4* ur = (const float4*)&sU[row*NH];
    float acc = 0.f;
    #pragma unroll
    for (int k4 = 0; k4 < 16; k4++){
      float4 u = ur[k4];
      acc += u.x*sW1[(k4*4+0)*NH+tx];
      acc += u.y*sW1[(k4*4+1)*NH+tx];
      acc += u.z*sW1[(k4*4+2)*NH+tx];
      acc += u.w*sW1[(k4*4+3)*NH+tx];
    }
    sV[row*NH + tx] = fmaxf(acc, 0.f);
  }
  __syncthreads();
  float ls1 = 0.f, ls2 = 0.f;
  for (int i = 0; i < 16; i++){
    int row = ty*16 + i;
    if (row >= nrows) break;
    const float4* vr = (const float4*)&sV[row*NH];
    float acc = 0.f;
    #pragma unroll
    for (int k4 = 0; k4 < 16; k4++){
      float4 v = vr[k4];
      acc += v.x*sW2[(k4*4+0)*NH+tx];
      acc += v.y*sW2[(k4*4+1)*NH+tx];
      acc += v.z*sW2[(k4*4+2)*NH+tx];
      acc += v.w*sW2[(k4*4+3)*NH+tx];
    }
    float tv = fmaxf(acc, 0.f);
    U[(size_t)node0*NH + row*NH + tx] = tv;
    ls1 += tv; ls2 += tv*tv;
  }
  __syncthreads();
  sW1[ty*NH + tx] = ls1;
  sW1[(4+ty)*NH + tx] = ls2;
  __syncthreads();
  if (ty == 0){
    float a1 = sW1[tx] + sW1[NH+tx] + sW1[2*NH+tx] + sW1[3*NH+tx];
    float a2 = sW1[4*NH+tx] + sW1[5*NH+tx] + sW1[6*NH+tx] + sW1[7*NH+tx];
    unsafeAtomicAdd(&s1[tx], a1);
    unsafeAtomicAdd(&s2[tx], a2);
  }
}

extern "C" void kernel_launch(void* const* d_in, const int* in_sizes, int n_in,
                              void* d_out, int out_size, void* d_ws, size_t ws_size,
                              hipStream_t stream) {
  const void* x    = d_in[0];
  const int* ei    = (const int*)d_in[1];
  const int* batch = (const int*)d_in[2];
  const void* Wt   = d_in[3];
  const void* bt   = d_in[4];
  const void* g0   = d_in[5];
  const void* b0   = d_in[6];
  const void* W1   = d_in[7];
  const void* W2   = d_in[8];
  const void* gs   = d_in[9];
  const void* bs   = d_in[10];

  float* hbuf = (float*)d_ws;           // NN*NH f32
  float* ubuf = hbuf + (size_t)NN*NH;   // NN*NH f32 (U, then in-place T)
  float* s1   = ubuf + (size_t)NN*NH;   // 64
  float* s2   = s1 + NH;                // 64
  float* scA  = s2 + NH;                // 64
  float* shB  = scA + NH;               // 64
  int* starts = (int*)(shB + NH);       // 512
  int* flag   = starts + 512;           // 64 (padded)
  int* deg    = flag + 64;              // NN
  int* rowptr = deg + NN;               // NN+64
  int* cursor = rowptr + NN + 64;       // NN
  int* csr    = cursor + NN;            // NE
  int* bsum   = csr + NE;               // 256

  hipMemsetAsync(s1, 0, 2*NH*sizeof(float), stream);
  hipMemsetAsync(deg, 0, NN*sizeof(int), stream);
  k_detect<<<1, 64, 0, stream>>>((const u32*)x, flag);
  k_bounds<<<1, 512, 0, stream>>>(batch, starts);
  k_count<<<(NE+255)/256, 256, 0, stream>>>(ei, deg);
  k_scanA<<<SCAN_B, 256, 0, stream>>>(deg, bsum);
  k_scanB<<<1, 256, 0, stream>>>(bsum);
  k_scanC<<<SCAN_B, 256, 0, stream>>>(deg, bsum, rowptr, cursor);
  k_fill<<<(NE+255)/256, 256, 0, stream>>>(ei, cursor, csr);

  k_transform_b<<<(NN+63)/64, 256, 0, stream>>>((const u16*)x, (const u16*)Wt, (const u16*)bt, flag, ubuf, s1, s2);
  k_transform_f<<<(NN+63)/64, 256, 0, stream>>>((const float*)x, (const float*)Wt, (const float*)bt, flag, ubuf, s1, s2);
  k_bnfinal<<<1, NH, 0, stream>>>(s1, s2, g0, b0, 0, flag, scA, shB);
  k_embed<<<NG, 256, 0, stream>>>(ubuf, scA, shB, hbuf, starts, flag, d_out, 0);

  for (int l = 0; l < 3; l++){
    k_gather<<<(NN+3)/4, 256, 0, stream>>>(hbuf, rowptr, csr, ubuf);
    k_mlp_b<<<(NN+63)/64, 256, 0, stream>>>(ubuf, (const u16*)W1, (const u16*)W2, l*NH*NH, flag, s1, s2);
    k_mlp_f<<<(NN+63)/64, 256, 0, stream>>>(ubuf, (const float*)W1, (const float*)W2, l*NH*NH, flag, s1, s2);
    k_bnfinal<<<1, NH, 0, stream>>>(s1, s2, gs, bs, l*NH, flag, scA, shB);
    k_embed<<<NG, 256, 0, stream>>>(ubuf, scA, shB, hbuf, starts, flag, d_out, l+1);
  }
}